// Round 1
// baseline (840.473 us; speedup 1.0000x reference)
//
#include <hip/hip_runtime.h>

#define C_N   512
#define E_N   261632

typedef _Float16 f16;
typedef _Float16 f16x4_t __attribute__((ext_vector_type(4)));
typedef _Float16 f16x8_t __attribute__((ext_vector_type(8)));
typedef float    f32x4_t __attribute__((ext_vector_type(4)));

// ---------------- K1a: SA/RB precompute (fp32, exact) ----------------
// SA[t][c][h] = sum_d inputs[c][d] * W1[t][d][h]
// RB[t][c][h] = sum_d inputs[c][d] * W1[t][256+d][h] + b1[t][h]
__global__ __launch_bounds__(256) void k_precompute(const float* __restrict__ inputs,
    const float* __restrict__ W1, const float* __restrict__ b1,
    float* __restrict__ SA, float* __restrict__ RB)
{
  int t  = blockIdx.x >> 7;            // 0..1
  int c0 = (blockIdx.x & 127) * 4;     // 4 nodes per block
  __shared__ float xs[4][256];
  for (int i = threadIdx.x; i < 1024; i += 256)
    xs[i >> 8][i & 255] = inputs[(size_t)(c0 + (i >> 8)) * 256 + (i & 255)];
  __syncthreads();
  const float* W1t = W1 + (size_t)t * 512 * 512;
  int h0 = threadIdx.x;
  float sa[2][4] = {{0.f}}, rbv[2][4] = {{0.f}};
  for (int d = 0; d < 256; d++) {
    float wt0 = W1t[d * 512 + h0];
    float wt1 = W1t[d * 512 + h0 + 256];
    float wb0 = W1t[(256 + d) * 512 + h0];
    float wb1 = W1t[(256 + d) * 512 + h0 + 256];
    #pragma unroll
    for (int r = 0; r < 4; r++) {
      float x = xs[r][d];
      sa[0][r]  += x * wt0; sa[1][r]  += x * wt1;
      rbv[0][r] += x * wb0; rbv[1][r] += x * wb1;
    }
  }
  #pragma unroll
  for (int hh = 0; hh < 2; hh++) {
    int h = h0 + hh * 256;
    float bb = b1[t * 512 + h];
    #pragma unroll
    for (int r = 0; r < 4; r++) {
      SA[((size_t)(t * 512 + c0 + r)) * 512 + h] = sa[hh][r];
      RB[((size_t)(t * 512 + c0 + r)) * 512 + h] = rbv[hh][r] + bb;
    }
  }
}

// ---------------- K1b: pack W2 into f16 B-fragment order ----------------
// W2p[((t*16+kc)*16+ct)*64 + lane][j] = W2[t][kc*32 + (lane>>4)*8 + j][ct*16 + (lane&15)]
__global__ __launch_bounds__(256) void k_pack_w2(const float* __restrict__ W2, f16* __restrict__ W2p)
{
  int gid  = blockIdx.x * 256 + threadIdx.x;   // 0..32767
  int lane = gid & 63;
  int ct   = (gid >> 6) & 15;
  int kc   = (gid >> 10) & 15;
  int t    = gid >> 14;
  int n    = ct * 16 + (lane & 15);
  int k0   = kc * 32 + (lane >> 4) * 8;
  const float* src = W2 + (size_t)t * 512 * 256;
  f16x8_t v;
  #pragma unroll
  for (int j = 0; j < 8; j++) v[j] = (f16)src[(size_t)(k0 + j) * 256 + n];
  *(f16x8_t*)(W2p + (size_t)gid * 8) = v;
}

// ---------------- counting sort of edges by rec_idx ----------------
__global__ void k_zero_hist(int* hist) { hist[threadIdx.x] = 0; }

__global__ __launch_bounds__(256) void k_hist(const int* __restrict__ rec, int* __restrict__ hist)
{
  __shared__ int lh[512];
  for (int i = threadIdx.x; i < 512; i += 256) lh[i] = 0;
  __syncthreads();
  for (int e = blockIdx.x * 256 + threadIdx.x; e < E_N; e += 256 * 256)
    atomicAdd(&lh[rec[e]], 1);
  __syncthreads();
  for (int i = threadIdx.x; i < 512; i += 256)
    if (lh[i]) atomicAdd(&hist[i], lh[i]);
}

__global__ void k_scan(const int* __restrict__ hist, int* __restrict__ seg, int* __restrict__ cursor)
{
  __shared__ int s[512];
  int tid = threadIdx.x;
  int v0 = hist[tid];
  s[tid] = v0;
  __syncthreads();
  for (int off = 1; off < 512; off <<= 1) {
    int v = (tid >= off) ? s[tid - off] : 0;
    __syncthreads();
    s[tid] += v;
    __syncthreads();
  }
  int excl = s[tid] - v0;
  seg[tid] = excl;
  cursor[tid] = excl;
  if (tid == 0) seg[512] = E_N;
}

__global__ __launch_bounds__(256) void k_scatter(const int* __restrict__ rec,
    int* __restrict__ cursor, int* __restrict__ sorted)
{
  for (int e = blockIdx.x * 256 + threadIdx.x; e < E_N; e += 256 * 256) {
    int pos = atomicAdd(&cursor[rec[e]], 1);
    sorted[pos] = e;
  }
}

// ---------------- K5: per-receiver edge MLP + aggregation ----------------
#define H1S 520   // f16 elems per h1 row: 512 + 8 pad (bank-conflict-free A reads)

__global__ __launch_bounds__(256, 2) void k_edges(
    const float* __restrict__ SA, const float* __restrict__ RB,
    const f16* __restrict__ W2p, const float* __restrict__ b2,
    const float* __restrict__ rel, const int* __restrict__ send_idx,
    const int* __restrict__ seg, const int* __restrict__ sorted,
    float* __restrict__ agg)
{
  __shared__ f16   h1[64 * H1S];      // 66560 B
  __shared__ float rbs[2][512];       // 4096 B
  __shared__ float aggL[256];         // 1024 B
  __shared__ float relv[64][2];       // 512 B
  __shared__ int   sends[64];         // 256 B

  int c    = blockIdx.x;              // this block owns receiver node c
  int tid  = threadIdx.x;
  int lane = tid & 63;
  int w    = tid >> 6;                // wave 0..3 -> cols 64w..64w+63
  int quad = lane >> 4;
  int lcol = lane & 15;

  for (int i = tid; i < 1024; i += 256)
    rbs[i >> 9][i & 511] = RB[((size_t)((i >> 9) * 512 + c)) * 512 + (i & 511)];
  aggL[tid] = 0.0f;

  int s0 = seg[c], s1 = seg[c + 1];

  for (int base = s0; base < s1; base += 64) {
    __syncthreads();
    if (tid < 64) {
      int pos = base + tid;
      if (pos < s1) {
        int e = sorted[pos];
        sends[tid]   = send_idx[e];
        relv[tid][0] = rel[2 * (size_t)e];
        relv[tid][1] = rel[2 * (size_t)e + 1];
      } else {
        sends[tid] = 0; relv[tid][0] = 0.0f; relv[tid][1] = 0.0f;
      }
    }
    __syncthreads();

    for (int t = 0; t < 2; t++) {
      // ---- build h1 = relu(SA[t][send] + RB[t][c]) as f16 ----
      const float4* SA4 = (const float4*)(SA + (size_t)t * 512 * 512);
      const float4* rb4 = (const float4*)rbs[t];
      for (int idx = tid; idx < 64 * 128; idx += 256) {
        int row = idx >> 7, q = idx & 127;
        float4 a  = SA4[(size_t)sends[row] * 128 + q];
        float4 bb = rb4[q];
        f16x4_t hv;
        hv[0] = (f16)fmaxf(a.x + bb.x, 0.0f);
        hv[1] = (f16)fmaxf(a.y + bb.y, 0.0f);
        hv[2] = (f16)fmaxf(a.z + bb.z, 0.0f);
        hv[3] = (f16)fmaxf(a.w + bb.w, 0.0f);
        *(f16x4_t*)&h1[row * H1S + q * 4] = hv;
      }
      __syncthreads();

      // ---- GEMM: msg[64,256] = h1[64,512] @ W2[t][512,256] via MFMA ----
      f32x4_t acc[4][4];
      #pragma unroll
      for (int rt = 0; rt < 4; rt++)
        #pragma unroll
        for (int ctl = 0; ctl < 4; ctl++)
          acc[rt][ctl] = (f32x4_t){0.f, 0.f, 0.f, 0.f};

      const f16x8_t* Bp = (const f16x8_t*)W2p;
      for (int kc = 0; kc < 16; kc++) {
        f16x8_t bfr[4];
        #pragma unroll
        for (int ctl = 0; ctl < 4; ctl++)
          bfr[ctl] = Bp[(size_t)(((t * 16 + kc) * 16 + (4 * w + ctl)) * 64 + lane)];
        #pragma unroll
        for (int rt = 0; rt < 4; rt++) {
          f16x8_t af = *(const f16x8_t*)&h1[(rt * 16 + lcol) * H1S + kc * 32 + quad * 8];
          #pragma unroll
          for (int ctl = 0; ctl < 4; ctl++)
            acc[rt][ctl] = __builtin_amdgcn_mfma_f32_16x16x32_f16(af, bfr[ctl], acc[rt][ctl], 0, 0, 0);
        }
      }

      // ---- epilogue: +b2, relu, *rel_type, reduce rows -> aggL ----
      #pragma unroll
      for (int ctl = 0; ctl < 4; ctl++) {
        int col = (4 * w + ctl) * 16 + lcol;
        float b2c = b2[t * 256 + col];
        float csum = 0.0f;
        #pragma unroll
        for (int rt = 0; rt < 4; rt++)
          #pragma unroll
          for (int r = 0; r < 4; r++) {
            int row = rt * 16 + quad * 4 + r;
            float v = fmaxf(acc[rt][ctl][r] + b2c, 0.0f);
            csum += v * relv[row][t];
          }
        csum += __shfl_xor(csum, 16, 64);
        csum += __shfl_xor(csum, 32, 64);
        if (quad == 0) aggL[col] += csum;   // waves own disjoint col ranges
      }
      __syncthreads();
    }
  }
  __syncthreads();
  agg[(size_t)c * 256 + tid] = aggL[tid];
}

// ---------------- K6: output MLP (2 rows per block, fp32) ----------------
__global__ __launch_bounds__(256) void k_out_mlp(const float* __restrict__ agg,
    const float* __restrict__ Wo1, const float* __restrict__ bo1,
    const float* __restrict__ Wo2, const float* __restrict__ bo2,
    const float* __restrict__ Wo3, const float* __restrict__ bo3,
    float* __restrict__ out)
{
  __shared__ float xs[2][256];
  __shared__ float h1s[2][512];
  __shared__ float h2s[2][512];
  int tid = threadIdx.x;
  int c0 = blockIdx.x * 2;
  for (int i = tid; i < 512; i += 256)
    xs[i >> 8][i & 255] = agg[(size_t)(c0 + (i >> 8)) * 256 + (i & 255)];
  __syncthreads();
  #pragma unroll
  for (int hh = 0; hh < 2; hh++) {
    int h = tid + hh * 256;
    float a0 = 0.f, a1 = 0.f;
    for (int m = 0; m < 256; m++) {
      float wv = Wo1[m * 512 + h];
      a0 += xs[0][m] * wv;
      a1 += xs[1][m] * wv;
    }
    float bb = bo1[h];
    h1s[0][h] = fmaxf(a0 + bb, 0.f);
    h1s[1][h] = fmaxf(a1 + bb, 0.f);
  }
  __syncthreads();
  #pragma unroll
  for (int hh = 0; hh < 2; hh++) {
    int h = tid + hh * 256;
    float a0 = 0.f, a1 = 0.f;
    for (int m = 0; m < 512; m++) {
      float wv = Wo2[m * 512 + h];
      a0 += h1s[0][m] * wv;
      a1 += h1s[1][m] * wv;
    }
    float bb = bo2[h];
    h2s[0][h] = fmaxf(a0 + bb, 0.f);
    h2s[1][h] = fmaxf(a1 + bb, 0.f);
  }
  __syncthreads();
  {
    int d = tid;
    float a0 = 0.f, a1 = 0.f;
    for (int m = 0; m < 512; m++) {
      float wv = Wo3[m * 256 + d];
      a0 += h2s[0][m] * wv;
      a1 += h2s[1][m] * wv;
    }
    out[(size_t)c0 * 256 + d]       = a0 + bo3[d];
    out[((size_t)c0 + 1) * 256 + d] = a1 + bo3[d];
  }
}

// ---------------- launcher ----------------
extern "C" void kernel_launch(void* const* d_in, const int* in_sizes, int n_in,
                              void* d_out, int out_size, void* d_ws, size_t ws_size,
                              hipStream_t stream)
{
  (void)in_sizes; (void)n_in; (void)out_size; (void)ws_size;
  const float* inputs = (const float*)d_in[0];
  const float* rel    = (const float*)d_in[1];
  const float* W1     = (const float*)d_in[2];
  const float* b1     = (const float*)d_in[3];
  const float* W2     = (const float*)d_in[4];
  const float* b2     = (const float*)d_in[5];
  const float* Wo1    = (const float*)d_in[6];
  const float* bo1    = (const float*)d_in[7];
  const float* Wo2    = (const float*)d_in[8];
  const float* bo2    = (const float*)d_in[9];
  const float* Wo3    = (const float*)d_in[10];
  const float* bo3    = (const float*)d_in[11];
  const int* send_idx = (const int*)d_in[12];
  const int* rec_idx  = (const int*)d_in[13];
  float* out = (float*)d_out;

  char* ws = (char*)d_ws;
  float* SA     = (float*)(ws + 0);                            // 2 MB
  float* RB     = (float*)(ws + (2u << 20));                   // 2 MB
  f16*   W2p    = (f16*)  (ws + (4u << 20));                   // 512 KB
  float* agg    = (float*)(ws + (4u << 20) + (512u << 10));    // 512 KB
  int*   hist   = (int*)  (ws + (5u << 20));                   // 2 KB
  int*   seg    = (int*)  (ws + (5u << 20) + 4096);            // 513 ints
  int*   cur    = (int*)  (ws + (5u << 20) + 8192);            // 512 ints
  int*   sorted = (int*)  (ws + (5u << 20) + 12288);           // ~1 MB

  k_precompute<<<dim3(256), dim3(256), 0, stream>>>(inputs, W1, b1, SA, RB);
  k_pack_w2   <<<dim3(128), dim3(256), 0, stream>>>(W2, W2p);
  k_zero_hist <<<dim3(1),   dim3(512), 0, stream>>>(hist);
  k_hist      <<<dim3(256), dim3(256), 0, stream>>>(rec_idx, hist);
  k_scan      <<<dim3(1),   dim3(512), 0, stream>>>(hist, seg, cur);
  k_scatter   <<<dim3(256), dim3(256), 0, stream>>>(rec_idx, cur, sorted);
  k_edges     <<<dim3(512), dim3(256), 0, stream>>>(SA, RB, W2p, b2, rel, send_idx, seg, sorted, agg);
  k_out_mlp   <<<dim3(256), dim3(256), 0, stream>>>(agg, Wo1, bo1, Wo2, bo2, Wo3, bo3, out);
}

// Round 2
// 697.151 us; speedup vs baseline: 1.2056x; 1.2056x over previous
//
#include <hip/hip_runtime.h>

#define C_N   512
#define E_N   261632

typedef _Float16 f16;
typedef _Float16 f16x4_t __attribute__((ext_vector_type(4)));
typedef _Float16 f16x8_t __attribute__((ext_vector_type(8)));
typedef float    f32x4_t __attribute__((ext_vector_type(4)));

// ---------------- K1a: SA/RB precompute (fp32 accumulate, f16 store) ----------------
// SA[t][c][h] = sum_d inputs[c][d] * W1[t][d][h]
// RB[t][c][h] = sum_d inputs[c][d] * W1[t][256+d][h] + b1[t][h]
__global__ __launch_bounds__(256) void k_precompute(const float* __restrict__ inputs,
    const float* __restrict__ W1, const float* __restrict__ b1,
    f16* __restrict__ SA, f16* __restrict__ RB)
{
  int t  = blockIdx.x >> 7;            // 0..1
  int c0 = (blockIdx.x & 127) * 4;     // 4 nodes per block
  __shared__ float xs[4][256];
  for (int i = threadIdx.x; i < 1024; i += 256)
    xs[i >> 8][i & 255] = inputs[(size_t)(c0 + (i >> 8)) * 256 + (i & 255)];
  __syncthreads();
  const float* W1t = W1 + (size_t)t * 512 * 512;
  int h0 = threadIdx.x;
  float sa[2][4] = {{0.f}}, rbv[2][4] = {{0.f}};
  for (int d = 0; d < 256; d++) {
    float wt0 = W1t[d * 512 + h0];
    float wt1 = W1t[d * 512 + h0 + 256];
    float wb0 = W1t[(256 + d) * 512 + h0];
    float wb1 = W1t[(256 + d) * 512 + h0 + 256];
    #pragma unroll
    for (int r = 0; r < 4; r++) {
      float x = xs[r][d];
      sa[0][r]  += x * wt0; sa[1][r]  += x * wt1;
      rbv[0][r] += x * wb0; rbv[1][r] += x * wb1;
    }
  }
  #pragma unroll
  for (int hh = 0; hh < 2; hh++) {
    int h = h0 + hh * 256;
    float bb = b1[t * 512 + h];
    #pragma unroll
    for (int r = 0; r < 4; r++) {
      SA[((size_t)(t * 512 + c0 + r)) * 512 + h] = (f16)sa[hh][r];
      RB[((size_t)(t * 512 + c0 + r)) * 512 + h] = (f16)(rbv[hh][r] + bb);
    }
  }
}

// ---------------- K1b: pack W2 into f16 B-fragment order ----------------
__global__ __launch_bounds__(256) void k_pack_w2(const float* __restrict__ W2, f16* __restrict__ W2p)
{
  int gid  = blockIdx.x * 256 + threadIdx.x;   // 0..32767
  int lane = gid & 63;
  int ct   = (gid >> 6) & 15;
  int kc   = (gid >> 10) & 15;
  int t    = gid >> 14;
  int n    = ct * 16 + (lane & 15);
  int k0   = kc * 32 + (lane >> 4) * 8;
  const float* src = W2 + (size_t)t * 512 * 256;
  f16x8_t v;
  #pragma unroll
  for (int j = 0; j < 8; j++) v[j] = (f16)src[(size_t)(k0 + j) * 256 + n];
  *(f16x8_t*)(W2p + (size_t)gid * 8) = v;
}

// ---------------- counting sort of edges by rec_idx ----------------
__global__ void k_zero_hist(int* hist) { hist[threadIdx.x] = 0; }

__global__ __launch_bounds__(256) void k_hist(const int* __restrict__ rec, int* __restrict__ hist)
{
  __shared__ int lh[512];
  for (int i = threadIdx.x; i < 512; i += 256) lh[i] = 0;
  __syncthreads();
  for (int e = blockIdx.x * 256 + threadIdx.x; e < E_N; e += 256 * 256)
    atomicAdd(&lh[rec[e]], 1);
  __syncthreads();
  for (int i = threadIdx.x; i < 512; i += 256)
    if (lh[i]) atomicAdd(&hist[i], lh[i]);
}

// seg: exclusive scan; cur: same values but padded 16 ints (64B) apart
__global__ void k_scan(const int* __restrict__ hist, int* __restrict__ seg, int* __restrict__ cur)
{
  __shared__ int s[512];
  int tid = threadIdx.x;
  int v0 = hist[tid];
  s[tid] = v0;
  __syncthreads();
  for (int off = 1; off < 512; off <<= 1) {
    int v = (tid >= off) ? s[tid - off] : 0;
    __syncthreads();
    s[tid] += v;
    __syncthreads();
  }
  int excl = s[tid] - v0;
  seg[tid] = excl;
  cur[tid * 16] = excl;
  if (tid == 0) seg[512] = E_N;
}

// two-level scatter: LDS hist -> one global atomic per (block,rec) -> LDS placement
__global__ __launch_bounds__(256) void k_scatter2(const int* __restrict__ rec,
    int* __restrict__ cur, int* __restrict__ sorted)
{
  __shared__ int lh[512];
  __shared__ int lbase[512];
  int e0 = blockIdx.x * (E_N / 256);   // E_N/256 == 1022 exactly
  for (int i = threadIdx.x; i < 512; i += 256) lh[i] = 0;
  __syncthreads();
  for (int i = threadIdx.x; i < E_N / 256; i += 256)
    atomicAdd(&lh[rec[e0 + i]], 1);
  __syncthreads();
  for (int i = threadIdx.x; i < 512; i += 256) {
    int cnt = lh[i];
    lbase[i] = cnt ? atomicAdd(&cur[i * 16], cnt) : 0;
    lh[i] = 0;
  }
  __syncthreads();
  for (int i = threadIdx.x; i < E_N / 256; i += 256) {
    int e = e0 + i;
    int r = rec[e];
    int p = lbase[r] + atomicAdd(&lh[r], 1);
    sorted[p] = e;
  }
}

// ---------------- K5: per-receiver edge MLP + aggregation ----------------
#define H1S 520   // f16 elems per h1 row: 512 + 8 pad

__global__ __launch_bounds__(256, 2) void k_edges(
    const f16* __restrict__ SA, const f16* __restrict__ RB,
    const f16* __restrict__ W2p, const float* __restrict__ b2,
    const float* __restrict__ rel, const int* __restrict__ send_idx,
    const int* __restrict__ seg, const int* __restrict__ sorted,
    float* __restrict__ agg)
{
  __shared__ f16   h1[64 * H1S];      // 66560 B
  __shared__ f16   rbs[2][512];       // 2048 B
  __shared__ float aggL[256];         // 1024 B
  __shared__ float relv[64][2];       // 512 B
  __shared__ int   sends[64];         // 256 B

  int c    = blockIdx.x;              // this block owns receiver node c
  int tid  = threadIdx.x;
  int lane = tid & 63;
  int w    = tid >> 6;                // wave 0..3 -> cols 64w..64w+63
  int quad = lane >> 4;
  int lcol = lane & 15;

  // stage RB rows for this receiver (both types), f16x8 vector loads
  for (int i = tid; i < 128; i += 256) {
    int t = i >> 6, q = i & 63;
    *(f16x8_t*)&rbs[t][q * 8] = *(const f16x8_t*)&RB[((size_t)(t * 512 + c)) * 512 + q * 8];
  }
  aggL[tid] = 0.0f;

  int s0 = seg[c], s1 = seg[c + 1];

  for (int base = s0; base < s1; base += 64) {
    __syncthreads();
    if (tid < 64) {
      int pos = base + tid;
      if (pos < s1) {
        int e = sorted[pos];
        sends[tid]   = send_idx[e];
        relv[tid][0] = rel[2 * (size_t)e];
        relv[tid][1] = rel[2 * (size_t)e + 1];
      } else {
        sends[tid] = 0; relv[tid][0] = 0.0f; relv[tid][1] = 0.0f;
      }
    }
    __syncthreads();

    for (int t = 0; t < 2; t++) {
      // ---- build h1 = relu(SA[t][send] + RB[t][c]) in f16 ----
      const f16x8_t* SA8 = (const f16x8_t*)(SA + (size_t)t * 512 * 512);
      for (int idx = tid; idx < 64 * 64; idx += 256) {
        int row = idx >> 6, q = idx & 63;
        f16x8_t a  = SA8[(size_t)sends[row] * 64 + q];
        f16x8_t bb = *(const f16x8_t*)&rbs[t][q * 8];
        f16x8_t hv;
        #pragma unroll
        for (int j = 0; j < 8; j++) {
          f16 v = (f16)(a[j] + bb[j]);
          hv[j] = (v > (f16)0.0f) ? v : (f16)0.0f;
        }
        *(f16x8_t*)&h1[row * H1S + q * 8] = hv;
      }
      __syncthreads();

      // ---- GEMM: msg[64,256] = h1[64,512] @ W2[t][512,256] via MFMA ----
      f32x4_t acc[4][4];
      #pragma unroll
      for (int rt = 0; rt < 4; rt++)
        #pragma unroll
        for (int ctl = 0; ctl < 4; ctl++)
          acc[rt][ctl] = (f32x4_t){0.f, 0.f, 0.f, 0.f};

      const f16x8_t* Bp = (const f16x8_t*)W2p;
      for (int kc = 0; kc < 16; kc++) {
        f16x8_t bfr[4];
        #pragma unroll
        for (int ctl = 0; ctl < 4; ctl++)
          bfr[ctl] = Bp[(size_t)(((t * 16 + kc) * 16 + (4 * w + ctl)) * 64 + lane)];
        #pragma unroll
        for (int rt = 0; rt < 4; rt++) {
          f16x8_t af = *(const f16x8_t*)&h1[(rt * 16 + lcol) * H1S + kc * 32 + quad * 8];
          #pragma unroll
          for (int ctl = 0; ctl < 4; ctl++)
            acc[rt][ctl] = __builtin_amdgcn_mfma_f32_16x16x32_f16(af, bfr[ctl], acc[rt][ctl], 0, 0, 0);
        }
      }

      // ---- epilogue: +b2, relu, *rel_type, reduce rows -> aggL ----
      #pragma unroll
      for (int ctl = 0; ctl < 4; ctl++) {
        int col = (4 * w + ctl) * 16 + lcol;
        float b2c = b2[t * 256 + col];
        float csum = 0.0f;
        #pragma unroll
        for (int rt = 0; rt < 4; rt++)
          #pragma unroll
          for (int r = 0; r < 4; r++) {
            int row = rt * 16 + quad * 4 + r;
            float v = fmaxf(acc[rt][ctl][r] + b2c, 0.0f);
            csum += v * relv[row][t];
          }
        csum += __shfl_xor(csum, 16, 64);
        csum += __shfl_xor(csum, 32, 64);
        if (quad == 0) aggL[col] += csum;   // waves own disjoint col ranges
      }
      __syncthreads();
    }
  }
  __syncthreads();
  agg[(size_t)c * 256 + tid] = aggL[tid];
}

// ---------------- K6: output MLP (2 rows per block, fp32) ----------------
__global__ __launch_bounds__(256) void k_out_mlp(const float* __restrict__ agg,
    const float* __restrict__ Wo1, const float* __restrict__ bo1,
    const float* __restrict__ Wo2, const float* __restrict__ bo2,
    const float* __restrict__ Wo3, const float* __restrict__ bo3,
    float* __restrict__ out)
{
  __shared__ float xs[2][256];
  __shared__ float h1s[2][512];
  __shared__ float h2s[2][512];
  int tid = threadIdx.x;
  int c0 = blockIdx.x * 2;
  for (int i = tid; i < 512; i += 256)
    xs[i >> 8][i & 255] = agg[(size_t)(c0 + (i >> 8)) * 256 + (i & 255)];
  __syncthreads();
  #pragma unroll
  for (int hh = 0; hh < 2; hh++) {
    int h = tid + hh * 256;
    float a0 = 0.f, a1 = 0.f;
    for (int m = 0; m < 256; m++) {
      float wv = Wo1[m * 512 + h];
      a0 += xs[0][m] * wv;
      a1 += xs[1][m] * wv;
    }
    float bb = bo1[h];
    h1s[0][h] = fmaxf(a0 + bb, 0.f);
    h1s[1][h] = fmaxf(a1 + bb, 0.f);
  }
  __syncthreads();
  #pragma unroll
  for (int hh = 0; hh < 2; hh++) {
    int h = tid + hh * 256;
    float a0 = 0.f, a1 = 0.f;
    for (int m = 0; m < 512; m++) {
      float wv = Wo2[m * 512 + h];
      a0 += h1s[0][m] * wv;
      a1 += h1s[1][m] * wv;
    }
    float bb = bo2[h];
    h2s[0][h] = fmaxf(a0 + bb, 0.f);
    h2s[1][h] = fmaxf(a1 + bb, 0.f);
  }
  __syncthreads();
  {
    int d = tid;
    float a0 = 0.f, a1 = 0.f;
    for (int m = 0; m < 512; m++) {
      float wv = Wo3[m * 256 + d];
      a0 += h2s[0][m] * wv;
      a1 += h2s[1][m] * wv;
    }
    out[(size_t)c0 * 256 + d]       = a0 + bo3[d];
    out[((size_t)c0 + 1) * 256 + d] = a1 + bo3[d];
  }
}

// ---------------- launcher ----------------
extern "C" void kernel_launch(void* const* d_in, const int* in_sizes, int n_in,
                              void* d_out, int out_size, void* d_ws, size_t ws_size,
                              hipStream_t stream)
{
  (void)in_sizes; (void)n_in; (void)out_size; (void)ws_size;
  const float* inputs = (const float*)d_in[0];
  const float* rel    = (const float*)d_in[1];
  const float* W1     = (const float*)d_in[2];
  const float* b1     = (const float*)d_in[3];
  const float* W2     = (const float*)d_in[4];
  const float* b2     = (const float*)d_in[5];
  const float* Wo1    = (const float*)d_in[6];
  const float* bo1    = (const float*)d_in[7];
  const float* Wo2    = (const float*)d_in[8];
  const float* bo2    = (const float*)d_in[9];
  const float* Wo3    = (const float*)d_in[10];
  const float* bo3    = (const float*)d_in[11];
  const int* send_idx = (const int*)d_in[12];
  const int* rec_idx  = (const int*)d_in[13];
  float* out = (float*)d_out;

  char* ws = (char*)d_ws;
  f16*   SA     = (f16*)  (ws + 0);                            // 1 MB
  f16*   RB     = (f16*)  (ws + (1u << 20));                   // 1 MB
  f16*   W2p    = (f16*)  (ws + (2u << 20));                   // 512 KB
  float* agg    = (float*)(ws + (2u << 20) + (512u << 10));    // 512 KB
  int*   hist   = (int*)  (ws + (3u << 20));                   // 2 KB
  int*   seg    = (int*)  (ws + (3u << 20) + 4096);            // 513 ints
  int*   cur    = (int*)  (ws + (3u << 20) + 8192);            // 32 KB padded
  int*   sorted = (int*)  (ws + (3u << 20) + 8192 + 32768);    // ~1 MB

  k_precompute<<<dim3(256), dim3(256), 0, stream>>>(inputs, W1, b1, SA, RB);
  k_pack_w2   <<<dim3(128), dim3(256), 0, stream>>>(W2, W2p);
  k_zero_hist <<<dim3(1),   dim3(512), 0, stream>>>(hist);
  k_hist      <<<dim3(256), dim3(256), 0, stream>>>(rec_idx, hist);
  k_scan      <<<dim3(1),   dim3(512), 0, stream>>>(hist, seg, cur);
  k_scatter2  <<<dim3(256), dim3(256), 0, stream>>>(rec_idx, cur, sorted);
  k_edges     <<<dim3(512), dim3(256), 0, stream>>>(SA, RB, W2p, b2, rel, send_idx, seg, sorted, agg);
  k_out_mlp   <<<dim3(256), dim3(256), 0, stream>>>(agg, Wo1, bo1, Wo2, bo2, Wo3, bo3, out);
}

// Round 3
// 377.629 us; speedup vs baseline: 2.2257x; 1.8461x over previous
//
#include <hip/hip_runtime.h>

#define C_N   512
#define E_N   261632

typedef _Float16 f16;
typedef _Float16 f16x4_t __attribute__((ext_vector_type(4)));
typedef _Float16 f16x8_t __attribute__((ext_vector_type(8)));
typedef float    f32x4_t __attribute__((ext_vector_type(4)));

// ---------------- K1a: SA/RB precompute (fp32 accumulate, f16 store) ----------------
__global__ __launch_bounds__(256) void k_precompute(const float* __restrict__ inputs,
    const float* __restrict__ W1, const float* __restrict__ b1,
    f16* __restrict__ SA, f16* __restrict__ RB)
{
  int t  = blockIdx.x >> 7;            // 0..1
  int c0 = (blockIdx.x & 127) * 4;     // 4 nodes per block
  __shared__ float xs[4][256];
  for (int i = threadIdx.x; i < 1024; i += 256)
    xs[i >> 8][i & 255] = inputs[(size_t)(c0 + (i >> 8)) * 256 + (i & 255)];
  __syncthreads();
  const float* W1t = W1 + (size_t)t * 512 * 512;
  int h0 = threadIdx.x;
  float sa[2][4] = {{0.f}}, rbv[2][4] = {{0.f}};
  for (int d = 0; d < 256; d++) {
    float wt0 = W1t[d * 512 + h0];
    float wt1 = W1t[d * 512 + h0 + 256];
    float wb0 = W1t[(256 + d) * 512 + h0];
    float wb1 = W1t[(256 + d) * 512 + h0 + 256];
    #pragma unroll
    for (int r = 0; r < 4; r++) {
      float x = xs[r][d];
      sa[0][r]  += x * wt0; sa[1][r]  += x * wt1;
      rbv[0][r] += x * wb0; rbv[1][r] += x * wb1;
    }
  }
  #pragma unroll
  for (int hh = 0; hh < 2; hh++) {
    int h = h0 + hh * 256;
    float bb = b1[t * 512 + h];
    #pragma unroll
    for (int r = 0; r < 4; r++) {
      SA[((size_t)(t * 512 + c0 + r)) * 512 + h] = (f16)sa[hh][r];
      RB[((size_t)(t * 512 + c0 + r)) * 512 + h] = (f16)(rbv[hh][r] + bb);
    }
  }
}

// ---------------- K1b: pack W2 into f16 B-fragment order ----------------
__global__ __launch_bounds__(256) void k_pack_w2(const float* __restrict__ W2, f16* __restrict__ W2p)
{
  int gid  = blockIdx.x * 256 + threadIdx.x;   // 0..32767
  int lane = gid & 63;
  int ct   = (gid >> 6) & 15;
  int kc   = (gid >> 10) & 15;
  int t    = gid >> 14;
  int n    = ct * 16 + (lane & 15);
  int k0   = kc * 32 + (lane >> 4) * 8;
  const float* src = W2 + (size_t)t * 512 * 256;
  f16x8_t v;
  #pragma unroll
  for (int j = 0; j < 8; j++) v[j] = (f16)src[(size_t)(k0 + j) * 256 + n];
  *(f16x8_t*)(W2p + (size_t)gid * 8) = v;
}

// ---------------- counting sort of edges by rec_idx ----------------
__global__ void k_zero_hist(int* hist) { hist[threadIdx.x] = 0; }

__global__ __launch_bounds__(256) void k_hist(const int* __restrict__ rec, int* __restrict__ hist)
{
  __shared__ int lh[512];
  for (int i = threadIdx.x; i < 512; i += 256) lh[i] = 0;
  __syncthreads();
  for (int e = blockIdx.x * 256 + threadIdx.x; e < E_N; e += 256 * 256)
    atomicAdd(&lh[rec[e]], 1);
  __syncthreads();
  for (int i = threadIdx.x; i < 512; i += 256)
    if (lh[i]) atomicAdd(&hist[i], lh[i]);
}

__global__ void k_scan(const int* __restrict__ hist, int* __restrict__ seg, int* __restrict__ cur)
{
  __shared__ int s[512];
  int tid = threadIdx.x;
  int v0 = hist[tid];
  s[tid] = v0;
  __syncthreads();
  for (int off = 1; off < 512; off <<= 1) {
    int v = (tid >= off) ? s[tid - off] : 0;
    __syncthreads();
    s[tid] += v;
    __syncthreads();
  }
  int excl = s[tid] - v0;
  seg[tid] = excl;
  cur[tid * 16] = excl;
  if (tid == 0) seg[512] = E_N;
}

__global__ __launch_bounds__(256) void k_scatter2(const int* __restrict__ rec,
    int* __restrict__ cur, int* __restrict__ sorted)
{
  __shared__ int lh[512];
  __shared__ int lbase[512];
  int e0 = blockIdx.x * (E_N / 256);   // E_N/256 == 1022 exactly
  for (int i = threadIdx.x; i < 512; i += 256) lh[i] = 0;
  __syncthreads();
  for (int i = threadIdx.x; i < E_N / 256; i += 256)
    atomicAdd(&lh[rec[e0 + i]], 1);
  __syncthreads();
  for (int i = threadIdx.x; i < 512; i += 256) {
    int cnt = lh[i];
    lbase[i] = cnt ? atomicAdd(&cur[i * 16], cnt) : 0;
    lh[i] = 0;
  }
  __syncthreads();
  for (int i = threadIdx.x; i < E_N / 256; i += 256) {
    int e = e0 + i;
    int r = rec[e];
    int p = lbase[r] + atomicAdd(&lh[r], 1);
    sorted[p] = e;
  }
}

// ---------------- K5: per-receiver edge MLP + aggregation (pipelined) ----------------
#define H1S 520   // f16 elems per h1 row: 512 + 8 pad

__global__ __launch_bounds__(256, 2) void k_edges(
    const f16* __restrict__ SA, const f16* __restrict__ RB,
    const f16* __restrict__ W2p, const float* __restrict__ b2,
    const float* __restrict__ rel, const int* __restrict__ send_idx,
    const int* __restrict__ seg, const int* __restrict__ sorted,
    float* __restrict__ agg)
{
  __shared__ f16   h1[64 * H1S];      // 66560 B
  __shared__ f16   rbs[2][512];       // 2048 B
  __shared__ float aggL[256];         // 1024 B
  __shared__ float relv2[2][64][2];   // 1024 B
  __shared__ int   sends2[2][64];     // 512 B

  int c    = blockIdx.x;
  int tid  = threadIdx.x;
  int lane = tid & 63;
  int w    = tid >> 6;
  int quad = lane >> 4;
  int lcol = lane & 15;
  int q    = tid & 63;      // 16B chunk index within a 512-f16 row (0..63)
  int rb0  = tid >> 6;      // base row for gather/build: rows rb0 + 4j

  for (int i = tid; i < 128; i += 256) {
    int t = i >> 6, qq = i & 63;
    *(f16x8_t*)&rbs[t][qq * 8] = *(const f16x8_t*)&RB[((size_t)(t * 512 + c)) * 512 + qq * 8];
  }
  aggL[tid] = 0.0f;

  int s0 = seg[c], s1 = seg[c + 1];
  int nt = (s1 - s0 + 63) >> 6;

  // prologue: tile-0 metadata
  if (nt > 0 && tid < 64) {
    int pos = s0 + tid;
    if (pos < s1) {
      int e = sorted[pos];
      sends2[0][tid]   = send_idx[e];
      relv2[0][tid][0] = rel[2 * (size_t)e];
      relv2[0][tid][1] = rel[2 * (size_t)e + 1];
    } else {
      sends2[0][tid] = 0; relv2[0][tid][0] = 0.f; relv2[0][tid][1] = 0.f;
    }
  }
  __syncthreads();

  f16x8_t g[16];
  const f16x8_t* SAc = (const f16x8_t*)SA;   // chunk pointer; row r of type t at (t*512+r)*64
  const f16x8_t* Bp  = (const f16x8_t*)W2p;

  if (nt > 0) {
    // prologue gather: (tile 0, t=0)
    #pragma unroll
    for (int j = 0; j < 16; j++)
      g[j] = SAc[(size_t)sends2[0][rb0 + 4 * j] * 64 + q];
  }

  for (int ph = 0; ph < 2 * nt; ph++) {
    int ti  = ph >> 1;
    int t   = ph & 1;
    int cur = ti & 1;
    int nxt = cur ^ 1;
    bool more = (ti + 1 < nt);

    // ---- build h1 from prefetched g ----
    {
      f16x8_t rbq = *(const f16x8_t*)&rbs[t][q * 8];
      #pragma unroll
      for (int j = 0; j < 16; j++) {
        int row = rb0 + 4 * j;
        f16x8_t hv;
        #pragma unroll
        for (int e = 0; e < 8; e++) {
          f16 v = (f16)(g[j][e] + rbq[e]);
          hv[e] = (v > (f16)0.0f) ? v : (f16)0.0f;
        }
        *(f16x8_t*)&h1[row * H1S + q * 8] = hv;
      }
    }
    __syncthreads();

    // next-tile metadata (during t=0 phase)
    if (t == 0 && more && tid < 64) {
      int pos = s0 + (ti + 1) * 64 + tid;
      if (pos < s1) {
        int e = sorted[pos];
        sends2[nxt][tid]   = send_idx[e];
        relv2[nxt][tid][0] = rel[2 * (size_t)e];
        relv2[nxt][tid][1] = rel[2 * (size_t)e + 1];
      } else {
        sends2[nxt][tid] = 0; relv2[nxt][tid][0] = 0.f; relv2[nxt][tid][1] = 0.f;
      }
    }

    // ---- GEMM: msg[64,256] = h1 @ W2[t] with B dbuf + cross-phase gather ----
    f32x4_t acc[4][4];
    #pragma unroll
    for (int rt = 0; rt < 4; rt++)
      #pragma unroll
      for (int ctl = 0; ctl < 4; ctl++)
        acc[rt][ctl] = (f32x4_t){0.f, 0.f, 0.f, 0.f};

    f16x8_t bb[2][4];
    #pragma unroll
    for (int ctl = 0; ctl < 4; ctl++)
      bb[0][ctl] = Bp[(size_t)(((t * 16 + 0) * 16 + (4 * w + ctl)) * 64 + lane)];
    #pragma unroll
    for (int ctl = 0; ctl < 4; ctl++)
      bb[1][ctl] = Bp[(size_t)(((t * 16 + 1) * 16 + (4 * w + ctl)) * 64 + lane)];

    // issue next phase's gather AFTER the first B loads (vmcnt FIFO: B waits
    // then only need vmcnt(16+4), gathers stay in flight the whole loop)
    if (t == 0) {
      #pragma unroll
      for (int j = 0; j < 16; j++)
        g[j] = SAc[(size_t)(512 + sends2[cur][rb0 + 4 * j]) * 64 + q];
    } else if (more) {
      #pragma unroll
      for (int j = 0; j < 16; j++)
        g[j] = SAc[(size_t)sends2[nxt][rb0 + 4 * j] * 64 + q];
    }

    for (int kc = 0; kc < 16; kc++) {
      int pb = kc & 1;
      #pragma unroll
      for (int rt = 0; rt < 4; rt++) {
        f16x8_t af = *(const f16x8_t*)&h1[(rt * 16 + lcol) * H1S + kc * 32 + quad * 8];
        #pragma unroll
        for (int ctl = 0; ctl < 4; ctl++)
          acc[rt][ctl] = __builtin_amdgcn_mfma_f32_16x16x32_f16(af, bb[pb][ctl], acc[rt][ctl], 0, 0, 0);
      }
      if (kc + 2 < 16) {
        #pragma unroll
        for (int ctl = 0; ctl < 4; ctl++)
          bb[pb][ctl] = Bp[(size_t)(((t * 16 + kc + 2) * 16 + (4 * w + ctl)) * 64 + lane)];
      }
    }

    // ---- epilogue: +b2, relu, *rel_type, reduce rows -> aggL ----
    #pragma unroll
    for (int ctl = 0; ctl < 4; ctl++) {
      int col = (4 * w + ctl) * 16 + lcol;
      float b2c = b2[t * 256 + col];
      float csum = 0.0f;
      #pragma unroll
      for (int rt = 0; rt < 4; rt++)
        #pragma unroll
        for (int r = 0; r < 4; r++) {
          int row = rt * 16 + quad * 4 + r;
          float v = fmaxf(acc[rt][ctl][r] + b2c, 0.0f);
          csum += v * relv2[cur][row][t];
        }
      csum += __shfl_xor(csum, 16, 64);
      csum += __shfl_xor(csum, 32, 64);
      if (quad == 0) aggL[col] += csum;
    }
    __syncthreads();
  }

  agg[(size_t)c * 256 + tid] = aggL[tid];
}

// ---------------- K6: output MLP (2 rows per block, fp32) ----------------
__global__ __launch_bounds__(256) void k_out_mlp(const float* __restrict__ agg,
    const float* __restrict__ Wo1, const float* __restrict__ bo1,
    const float* __restrict__ Wo2, const float* __restrict__ bo2,
    const float* __restrict__ Wo3, const float* __restrict__ bo3,
    float* __restrict__ out)
{
  __shared__ float xs[2][256];
  __shared__ float h1s[2][512];
  __shared__ float h2s[2][512];
  int tid = threadIdx.x;
  int c0 = blockIdx.x * 2;
  for (int i = tid; i < 512; i += 256)
    xs[i >> 8][i & 255] = agg[(size_t)(c0 + (i >> 8)) * 256 + (i & 255)];
  __syncthreads();
  #pragma unroll
  for (int hh = 0; hh < 2; hh++) {
    int h = tid + hh * 256;
    float a0 = 0.f, a1 = 0.f;
    for (int m = 0; m < 256; m++) {
      float wv = Wo1[m * 512 + h];
      a0 += xs[0][m] * wv;
      a1 += xs[1][m] * wv;
    }
    float bb = bo1[h];
    h1s[0][h] = fmaxf(a0 + bb, 0.f);
    h1s[1][h] = fmaxf(a1 + bb, 0.f);
  }
  __syncthreads();
  #pragma unroll
  for (int hh = 0; hh < 2; hh++) {
    int h = tid + hh * 256;
    float a0 = 0.f, a1 = 0.f;
    for (int m = 0; m < 512; m++) {
      float wv = Wo2[m * 512 + h];
      a0 += h1s[0][m] * wv;
      a1 += h1s[1][m] * wv;
    }
    float bb = bo2[h];
    h2s[0][h] = fmaxf(a0 + bb, 0.f);
    h2s[1][h] = fmaxf(a1 + bb, 0.f);
  }
  __syncthreads();
  {
    int d = tid;
    float a0 = 0.f, a1 = 0.f;
    for (int m = 0; m < 512; m++) {
      float wv = Wo3[m * 256 + d];
      a0 += h2s[0][m] * wv;
      a1 += h2s[1][m] * wv;
    }
    out[(size_t)c0 * 256 + d]       = a0 + bo3[d];
    out[((size_t)c0 + 1) * 256 + d] = a1 + bo3[d];
  }
}

// ---------------- launcher ----------------
extern "C" void kernel_launch(void* const* d_in, const int* in_sizes, int n_in,
                              void* d_out, int out_size, void* d_ws, size_t ws_size,
                              hipStream_t stream)
{
  (void)in_sizes; (void)n_in; (void)out_size; (void)ws_size;
  const float* inputs = (const float*)d_in[0];
  const float* rel    = (const float*)d_in[1];
  const float* W1     = (const float*)d_in[2];
  const float* b1     = (const float*)d_in[3];
  const float* W2     = (const float*)d_in[4];
  const float* b2     = (const float*)d_in[5];
  const float* Wo1    = (const float*)d_in[6];
  const float* bo1    = (const float*)d_in[7];
  const float* Wo2    = (const float*)d_in[8];
  const float* bo2    = (const float*)d_in[9];
  const float* Wo3    = (const float*)d_in[10];
  const float* bo3    = (const float*)d_in[11];
  const int* send_idx = (const int*)d_in[12];
  const int* rec_idx  = (const int*)d_in[13];
  float* out = (float*)d_out;

  char* ws = (char*)d_ws;
  f16*   SA     = (f16*)  (ws + 0);                            // 1 MB
  f16*   RB     = (f16*)  (ws + (1u << 20));                   // 1 MB
  f16*   W2p    = (f16*)  (ws + (2u << 20));                   // 512 KB
  float* agg    = (float*)(ws + (2u << 20) + (512u << 10));    // 512 KB
  int*   hist   = (int*)  (ws + (3u << 20));                   // 2 KB
  int*   seg    = (int*)  (ws + (3u << 20) + 4096);            // 513 ints
  int*   cur    = (int*)  (ws + (3u << 20) + 8192);            // 32 KB padded
  int*   sorted = (int*)  (ws + (3u << 20) + 8192 + 32768);    // ~1 MB

  k_precompute<<<dim3(256), dim3(256), 0, stream>>>(inputs, W1, b1, SA, RB);
  k_pack_w2   <<<dim3(128), dim3(256), 0, stream>>>(W2, W2p);
  k_zero_hist <<<dim3(1),   dim3(512), 0, stream>>>(hist);
  k_hist      <<<dim3(256), dim3(256), 0, stream>>>(rec_idx, hist);
  k_scan      <<<dim3(1),   dim3(512), 0, stream>>>(hist, seg, cur);
  k_scatter2  <<<dim3(256), dim3(256), 0, stream>>>(rec_idx, cur, sorted);
  k_edges     <<<dim3(512), dim3(256), 0, stream>>>(SA, RB, W2p, b2, rel, send_idx, seg, sorted, agg);
  k_out_mlp   <<<dim3(256), dim3(256), 0, stream>>>(agg, Wo1, bo1, Wo2, bo2, Wo3, bo3, out);
}

// Round 4
// 370.137 us; speedup vs baseline: 2.2707x; 1.0202x over previous
//
#include <hip/hip_runtime.h>

#define C_N   512
#define E_N   261632

typedef _Float16 f16;
typedef _Float16 f16x4_t __attribute__((ext_vector_type(4)));
typedef _Float16 f16x8_t __attribute__((ext_vector_type(8)));
typedef float    f32x4_t __attribute__((ext_vector_type(4)));

// ---------------- fused prep: precompute SA/RB + pack W2 + hist partials ----------------
// blocks [0,256): SA/RB precompute; [256,384): pack W2; [384,448): 64 hist partials
__global__ __launch_bounds__(256) void k_prep(const float* __restrict__ inputs,
    const float* __restrict__ W1, const float* __restrict__ b1,
    const float* __restrict__ W2, const int* __restrict__ rec,
    f16* __restrict__ SA, f16* __restrict__ RB, f16* __restrict__ W2p,
    int* __restrict__ hist_part)
{
  int bid = blockIdx.x;
  if (bid < 256) {
    int t  = bid >> 7;
    int c0 = (bid & 127) * 4;
    __shared__ float xs[4][256];
    for (int i = threadIdx.x; i < 1024; i += 256)
      xs[i >> 8][i & 255] = inputs[(size_t)(c0 + (i >> 8)) * 256 + (i & 255)];
    __syncthreads();
    const float* W1t = W1 + (size_t)t * 512 * 512;
    int h0 = threadIdx.x;
    float sa[2][4] = {{0.f}}, rbv[2][4] = {{0.f}};
    for (int d = 0; d < 256; d++) {
      float wt0 = W1t[d * 512 + h0];
      float wt1 = W1t[d * 512 + h0 + 256];
      float wb0 = W1t[(256 + d) * 512 + h0];
      float wb1 = W1t[(256 + d) * 512 + h0 + 256];
      #pragma unroll
      for (int r = 0; r < 4; r++) {
        float x = xs[r][d];
        sa[0][r]  += x * wt0; sa[1][r]  += x * wt1;
        rbv[0][r] += x * wb0; rbv[1][r] += x * wb1;
      }
    }
    #pragma unroll
    for (int hh = 0; hh < 2; hh++) {
      int h = h0 + hh * 256;
      float bb = b1[t * 512 + h];
      #pragma unroll
      for (int r = 0; r < 4; r++) {
        SA[((size_t)(t * 512 + c0 + r)) * 512 + h] = (f16)sa[hh][r];
        RB[((size_t)(t * 512 + c0 + r)) * 512 + h] = (f16)(rbv[hh][r] + bb);
      }
    }
  } else if (bid < 384) {
    int gid  = (bid - 256) * 256 + threadIdx.x;   // 0..32767
    int lane = gid & 63;
    int ct   = (gid >> 6) & 15;
    int kc   = (gid >> 10) & 15;
    int t    = gid >> 14;
    int n    = ct * 16 + (lane & 15);
    int k0   = kc * 32 + (lane >> 4) * 8;
    const float* src = W2 + (size_t)t * 512 * 256;
    f16x8_t v;
    #pragma unroll
    for (int j = 0; j < 8; j++) v[j] = (f16)src[(size_t)(k0 + j) * 256 + n];
    *(f16x8_t*)(W2p + (size_t)gid * 8) = v;
  } else {
    int hb = bid - 384;                 // 0..63
    __shared__ int lh[512];
    for (int i = threadIdx.x; i < 512; i += 256) lh[i] = 0;
    __syncthreads();
    int e0 = hb * (E_N / 64);           // E_N/64 == 4088 exactly
    for (int i = threadIdx.x; i < E_N / 64; i += 256)
      atomicAdd(&lh[rec[e0 + i]], 1);
    __syncthreads();
    for (int i = threadIdx.x; i < 512; i += 256)
      hist_part[hb * 512 + i] = lh[i];
  }
}

// ---------------- scan: reduce partials + exclusive scan ----------------
__global__ void k_scan(const int* __restrict__ hist_part, int* __restrict__ seg, int* __restrict__ cur)
{
  __shared__ int s[512];
  int tid = threadIdx.x;
  int v0 = 0;
  #pragma unroll 8
  for (int b = 0; b < 64; b++) v0 += hist_part[b * 512 + tid];
  s[tid] = v0;
  __syncthreads();
  for (int off = 1; off < 512; off <<= 1) {
    int v = (tid >= off) ? s[tid - off] : 0;
    __syncthreads();
    s[tid] += v;
    __syncthreads();
  }
  int excl = s[tid] - v0;
  seg[tid] = excl;
  cur[tid * 16] = excl;
  if (tid == 0) seg[512] = E_N;
}

// ---------------- two-level scatter ----------------
__global__ __launch_bounds__(256) void k_scatter2(const int* __restrict__ rec,
    int* __restrict__ cur, int* __restrict__ sorted)
{
  __shared__ int lh[512];
  __shared__ int lbase[512];
  int e0 = blockIdx.x * (E_N / 256);   // 1022 exactly
  for (int i = threadIdx.x; i < 512; i += 256) lh[i] = 0;
  __syncthreads();
  for (int i = threadIdx.x; i < E_N / 256; i += 256)
    atomicAdd(&lh[rec[e0 + i]], 1);
  __syncthreads();
  for (int i = threadIdx.x; i < 512; i += 256) {
    int cnt = lh[i];
    lbase[i] = cnt ? atomicAdd(&cur[i * 16], cnt) : 0;
    lh[i] = 0;
  }
  __syncthreads();
  for (int i = threadIdx.x; i < E_N / 256; i += 256) {
    int e = e0 + i;
    int r = rec[e];
    int p = lbase[r] + atomicAdd(&lh[r], 1);
    sorted[p] = e;
  }
}

// ---------------- K5: per-receiver edge MLP + aggregation (512 thr, pipelined) ----------------
#define H1S 520   // f16 elems per h1 row: 512 + 8 pad

__global__ __launch_bounds__(512, 4) void k_edges(
    const f16* __restrict__ SA, const f16* __restrict__ RB,
    const f16* __restrict__ W2p, const float* __restrict__ b2,
    const float* __restrict__ rel, const int* __restrict__ send_idx,
    const int* __restrict__ seg, const int* __restrict__ sorted,
    float* __restrict__ agg)
{
  __shared__ f16   h1[64 * H1S];      // 66560 B
  __shared__ f16   rbs[2][512];       // 2048 B
  __shared__ float aggL[256];         // 1024 B
  __shared__ float relv2[2][64][2];   // 1024 B
  __shared__ int   sends2[2][64];     // 512 B

  int c    = blockIdx.x;
  int tid  = threadIdx.x;             // 0..511
  int lane = tid & 63;
  int w    = tid >> 6;                // wave 0..7 -> col tiles 2w, 2w+1
  int quad = lane >> 4;
  int lcol = lane & 15;
  int q    = tid & 63;                // 16B chunk index in a row
  int rb0  = tid >> 6;                // base row: rows rb0 + 8j

  if (tid < 128) {
    int t = tid >> 6, qq = tid & 63;
    *(f16x8_t*)&rbs[t][qq * 8] = *(const f16x8_t*)&RB[((size_t)(t * 512 + c)) * 512 + qq * 8];
  }
  if (tid < 256) aggL[tid] = 0.0f;

  int s0 = seg[c], s1 = seg[c + 1];
  int nt = (s1 - s0 + 63) >> 6;

  if (nt > 0 && tid < 64) {
    int pos = s0 + tid;
    if (pos < s1) {
      int e = sorted[pos];
      sends2[0][tid]   = send_idx[e];
      relv2[0][tid][0] = rel[2 * (size_t)e];
      relv2[0][tid][1] = rel[2 * (size_t)e + 1];
    } else {
      sends2[0][tid] = 0; relv2[0][tid][0] = 0.f; relv2[0][tid][1] = 0.f;
    }
  }
  __syncthreads();

  f16x8_t g[8];
  const f16x8_t* SAc = (const f16x8_t*)SA;
  const f16x8_t* Bp  = (const f16x8_t*)W2p;

  if (nt > 0) {
    #pragma unroll
    for (int j = 0; j < 8; j++)
      g[j] = SAc[(size_t)sends2[0][rb0 + 8 * j] * 64 + q];
  }

  for (int ph = 0; ph < 2 * nt; ph++) {
    int ti  = ph >> 1;
    int t   = ph & 1;
    int cur = ti & 1;
    int nxt = cur ^ 1;
    bool more = (ti + 1 < nt);

    // ---- build h1 from prefetched g ----
    {
      f16x8_t rbq = *(const f16x8_t*)&rbs[t][q * 8];
      #pragma unroll
      for (int j = 0; j < 8; j++) {
        int row = rb0 + 8 * j;
        f16x8_t hv;
        #pragma unroll
        for (int e = 0; e < 8; e++) {
          f16 v = (f16)(g[j][e] + rbq[e]);
          hv[e] = (v > (f16)0.0f) ? v : (f16)0.0f;
        }
        *(f16x8_t*)&h1[row * H1S + q * 8] = hv;
      }
    }
    __syncthreads();

    if (t == 0 && more && tid < 64) {
      int pos = s0 + (ti + 1) * 64 + tid;
      if (pos < s1) {
        int e = sorted[pos];
        sends2[nxt][tid]   = send_idx[e];
        relv2[nxt][tid][0] = rel[2 * (size_t)e];
        relv2[nxt][tid][1] = rel[2 * (size_t)e + 1];
      } else {
        sends2[nxt][tid] = 0; relv2[nxt][tid][0] = 0.f; relv2[nxt][tid][1] = 0.f;
      }
    }

    f32x4_t acc[4][2];
    #pragma unroll
    for (int rt = 0; rt < 4; rt++)
      #pragma unroll
      for (int ctl = 0; ctl < 2; ctl++)
        acc[rt][ctl] = (f32x4_t){0.f, 0.f, 0.f, 0.f};

    f16x8_t bb[2][2];
    #pragma unroll
    for (int ctl = 0; ctl < 2; ctl++)
      bb[0][ctl] = Bp[(size_t)(((t * 16 + 0) * 16 + (2 * w + ctl)) * 64 + lane)];
    #pragma unroll
    for (int ctl = 0; ctl < 2; ctl++)
      bb[1][ctl] = Bp[(size_t)(((t * 16 + 1) * 16 + (2 * w + ctl)) * 64 + lane)];

    // cross-phase gather issued after first B loads (stays in flight across kc loop)
    if (t == 0) {
      #pragma unroll
      for (int j = 0; j < 8; j++)
        g[j] = SAc[(size_t)(512 + sends2[cur][rb0 + 8 * j]) * 64 + q];
    } else if (more) {
      #pragma unroll
      for (int j = 0; j < 8; j++)
        g[j] = SAc[(size_t)sends2[nxt][rb0 + 8 * j] * 64 + q];
    }

    for (int kc = 0; kc < 16; kc++) {
      int pb = kc & 1;
      #pragma unroll
      for (int rt = 0; rt < 4; rt++) {
        f16x8_t af = *(const f16x8_t*)&h1[(rt * 16 + lcol) * H1S + kc * 32 + quad * 8];
        #pragma unroll
        for (int ctl = 0; ctl < 2; ctl++)
          acc[rt][ctl] = __builtin_amdgcn_mfma_f32_16x16x32_f16(af, bb[pb][ctl], acc[rt][ctl], 0, 0, 0);
      }
      if (kc + 2 < 16) {
        #pragma unroll
        for (int ctl = 0; ctl < 2; ctl++)
          bb[pb][ctl] = Bp[(size_t)(((t * 16 + kc + 2) * 16 + (2 * w + ctl)) * 64 + lane)];
      }
    }

    #pragma unroll
    for (int ctl = 0; ctl < 2; ctl++) {
      int col = (2 * w + ctl) * 16 + lcol;
      float b2c = b2[t * 256 + col];
      float csum = 0.0f;
      #pragma unroll
      for (int rt = 0; rt < 4; rt++)
        #pragma unroll
        for (int r = 0; r < 4; r++) {
          int row = rt * 16 + quad * 4 + r;
          float v = fmaxf(acc[rt][ctl][r] + b2c, 0.0f);
          csum += v * relv2[cur][row][t];
        }
      csum += __shfl_xor(csum, 16, 64);
      csum += __shfl_xor(csum, 32, 64);
      if (quad == 0) aggL[col] += csum;
    }
    __syncthreads();
  }

  if (tid < 256) agg[(size_t)c * 256 + tid] = aggL[tid];
}

// ---------------- K6: output MLP (2 rows per block, fp32) ----------------
__global__ __launch_bounds__(256) void k_out_mlp(const float* __restrict__ agg,
    const float* __restrict__ Wo1, const float* __restrict__ bo1,
    const float* __restrict__ Wo2, const float* __restrict__ bo2,
    const float* __restrict__ Wo3, const float* __restrict__ bo3,
    float* __restrict__ out)
{
  __shared__ float xs[2][256];
  __shared__ float h1s[2][512];
  __shared__ float h2s[2][512];
  int tid = threadIdx.x;
  int c0 = blockIdx.x * 2;
  for (int i = tid; i < 512; i += 256)
    xs[i >> 8][i & 255] = agg[(size_t)(c0 + (i >> 8)) * 256 + (i & 255)];
  __syncthreads();
  #pragma unroll
  for (int hh = 0; hh < 2; hh++) {
    int h = tid + hh * 256;
    float a0 = 0.f, a1 = 0.f;
    for (int m = 0; m < 256; m++) {
      float wv = Wo1[m * 512 + h];
      a0 += xs[0][m] * wv;
      a1 += xs[1][m] * wv;
    }
    float bb = bo1[h];
    h1s[0][h] = fmaxf(a0 + bb, 0.f);
    h1s[1][h] = fmaxf(a1 + bb, 0.f);
  }
  __syncthreads();
  #pragma unroll
  for (int hh = 0; hh < 2; hh++) {
    int h = tid + hh * 256;
    float a0 = 0.f, a1 = 0.f;
    for (int m = 0; m < 512; m++) {
      float wv = Wo2[m * 512 + h];
      a0 += h1s[0][m] * wv;
      a1 += h1s[1][m] * wv;
    }
    float bb = bo2[h];
    h2s[0][h] = fmaxf(a0 + bb, 0.f);
    h2s[1][h] = fmaxf(a1 + bb, 0.f);
  }
  __syncthreads();
  {
    int d = tid;
    float a0 = 0.f, a1 = 0.f;
    for (int m = 0; m < 512; m++) {
      float wv = Wo3[m * 256 + d];
      a0 += h2s[0][m] * wv;
      a1 += h2s[1][m] * wv;
    }
    out[(size_t)c0 * 256 + d]       = a0 + bo3[d];
    out[((size_t)c0 + 1) * 256 + d] = a1 + bo3[d];
  }
}

// ---------------- launcher ----------------
extern "C" void kernel_launch(void* const* d_in, const int* in_sizes, int n_in,
                              void* d_out, int out_size, void* d_ws, size_t ws_size,
                              hipStream_t stream)
{
  (void)in_sizes; (void)n_in; (void)out_size; (void)ws_size;
  const float* inputs = (const float*)d_in[0];
  const float* rel    = (const float*)d_in[1];
  const float* W1     = (const float*)d_in[2];
  const float* b1     = (const float*)d_in[3];
  const float* W2     = (const float*)d_in[4];
  const float* b2     = (const float*)d_in[5];
  const float* Wo1    = (const float*)d_in[6];
  const float* bo1    = (const float*)d_in[7];
  const float* Wo2    = (const float*)d_in[8];
  const float* bo2    = (const float*)d_in[9];
  const float* Wo3    = (const float*)d_in[10];
  const float* bo3    = (const float*)d_in[11];
  const int* send_idx = (const int*)d_in[12];
  const int* rec_idx  = (const int*)d_in[13];
  float* out = (float*)d_out;

  char* ws = (char*)d_ws;
  f16*   SA        = (f16*)  (ws + 0);                            // 1 MB
  f16*   RB        = (f16*)  (ws + (1u << 20));                   // 1 MB
  f16*   W2p       = (f16*)  (ws + (2u << 20));                   // 512 KB
  float* agg       = (float*)(ws + (2u << 20) + (512u << 10));    // 512 KB
  int*   hist_part = (int*)  agg;                                 // 128 KB, consumed before agg is written
  int*   seg       = (int*)  (ws + (3u << 20) + 4096);            // 513 ints
  int*   cur       = (int*)  (ws + (3u << 20) + 8192);            // 32 KB padded
  int*   sorted    = (int*)  (ws + (3u << 20) + 8192 + 32768);    // ~1 MB

  k_prep    <<<dim3(448), dim3(256), 0, stream>>>(inputs, W1, b1, W2, rec_idx, SA, RB, W2p, hist_part);
  k_scan    <<<dim3(1),   dim3(512), 0, stream>>>(hist_part, seg, cur);
  k_scatter2<<<dim3(256), dim3(256), 0, stream>>>(rec_idx, cur, sorted);
  k_edges   <<<dim3(512), dim3(512), 0, stream>>>(SA, RB, W2p, b2, rel, send_idx, seg, sorted, agg);
  k_out_mlp <<<dim3(256), dim3(256), 0, stream>>>(agg, Wo1, bo1, Wo2, bo2, Wo3, bo3, out);
}